// Round 3
// baseline (169.713 us; speedup 1.0000x reference)
//
#include <hip/hip_runtime.h>
#include <hip/hip_fp16.h>

// JointSparseEmbedding: out[b, t, :] = float32(fp16(weights[cat[b, t] + offsets[t], :]))
// B=32768, T=26 tables, D=128, joint table rows = 2,600,000.
//
// Reference output dtype is float16 -> harness stores/compares it as FLOAT32
// ("else float*"). So d_out is a 436 MB f32 buffer; we write fp16-rounded
// values widened to f32.
//
// Memory-bound gather: ~436 MB random 512 B-row reads (fully consumed) +
// 436 MB streaming f32 writes. 32 lanes per row: float4 load, float4 store.

#define EMB_BATCH 32768
#define EMB_TABLES 26
#define EMB_DIM 128
#define EMB_ROWS (EMB_BATCH * EMB_TABLES)   // 851,968 output rows
#define ROWS_PER_BLOCK 8                     // 256 threads / 32 lanes-per-row

__global__ __launch_bounds__(256) void JointSparseEmbedding_3496103379186_kernel(
    const void* __restrict__ cat_raw,    // [B*T] categorical indices (i32 or i64)
    const float* __restrict__ weights,   // [2.6M * 128] fp32 joint table
    const void* __restrict__ off_raw,    // [T] per-table base offsets (i32 or i64)
    float* __restrict__ out)             // [B*T*128] f32 output (fp16-rounded)
{
    const int r = blockIdx.x * ROWS_PER_BLOCK + (threadIdx.x >> 5);  // output row id
    if (r >= EMB_ROWS) return;
    const int c = threadIdx.x & 31;          // float4 chunk within the row (0..31)

    // Sniff index width: int64 entries (<2.6M) have zero high words; an int32
    // buffer's "high words" are real indices uniform in [0,100000) -> all-zero
    // probability ~1e-40. Cached broadcast loads, wave-uniform branch.
    const unsigned int* raw32 = (const unsigned int*)cat_raw;
    bool is64 = true;
    #pragma unroll
    for (int i = 0; i < 8; ++i) is64 = is64 && (raw32[2 * i + 1] == 0u);

    const int t = r % EMB_TABLES;            // table id (magic-multiply)

    long long row;
    if (is64) {
        row = ((const long long*)cat_raw)[r] + ((const long long*)off_raw)[t];
    } else {
        row = (long long)((const int*)cat_raw)[r]
            + (long long)((const int*)off_raw)[t];
    }

    // 32 lanes x 16 B = 512 B contiguous read of the gathered row
    const float4* __restrict__ wrow =
        reinterpret_cast<const float4*>(weights + (size_t)row * EMB_DIM);
    float4 v = wrow[c];

    // fp16 round-to-nearest-even, widened back to f32 (matches ref exactly)
    v.x = __half2float(__float2half(v.x));
    v.y = __half2float(__float2half(v.y));
    v.z = __half2float(__float2half(v.z));
    v.w = __half2float(__float2half(v.w));

    // 32 lanes x 16 B = 512 B contiguous write per row; rows in a block are
    // consecutive -> 4 KB contiguous store per block.
    reinterpret_cast<float4*>(out + (size_t)r * EMB_DIM)[c] = v;
}

extern "C" void kernel_launch(void* const* d_in, const int* in_sizes, int n_in,
                              void* d_out, int out_size, void* d_ws, size_t ws_size,
                              hipStream_t stream) {
    const void* cat = d_in[0];                         // [B*T] integer indices
    const float* weights = (const float*)d_in[1];      // [2.6M*128] fp32
    const void* offsets = d_in[2];                     // [T] integer offsets
    float* out = (float*)d_out;

    const int blocks = EMB_ROWS / ROWS_PER_BLOCK;      // 851,968 / 8 = 106,496 exact
    JointSparseEmbedding_3496103379186_kernel<<<blocks, 256, 0, stream>>>(
        cat, weights, offsets, out);
}

// Round 5
// 136.181 us; speedup vs baseline: 1.2462x; 1.2462x over previous
//
#include <hip/hip_runtime.h>
#include <hip/hip_fp16.h>

// JointSparseEmbedding: out[b, t, :] = float32(fp16(weights[cat[b, t] + offsets[t], :]))
// B=32768, T=26 tables, D=128, joint table rows = 2,600,000.
//
// d_out is f32 (reference output fp16 -> harness "else float*" path); we write
// fp16-RNE values widened to f32 (bit-exact vs ref, absmax 0.0 in R3).
//
// R3: 169.7 us = 5.18 TB/s effective (879 MB total). Harness fill kernels show
// 6.55 TB/s streaming ceiling on this chip. This round: nontemporal output
// stores (write-once output -> don't thrash L2/L3, keep caches for the ~15%
// duplicate gather rows) + 2 rows per thread for MLP=2.
// Note: __builtin_nontemporal_store needs a clang ext_vector, not HIP float4.

#define EMB_BATCH 32768
#define EMB_TABLES 26
#define EMB_DIM 128
#define EMB_ROWS (EMB_BATCH * EMB_TABLES)   // 851,968 output rows
#define ROWS_PER_BLOCK 16                    // 256 threads / 32 lanes-per-row x 2

typedef float f32x4 __attribute__((ext_vector_type(4)));

__global__ __launch_bounds__(256) void JointSparseEmbedding_3496103379186_kernel(
    const void* __restrict__ cat_raw,    // [B*T] categorical indices (i32 or i64)
    const float* __restrict__ weights,   // [2.6M * 128] fp32 joint table
    const void* __restrict__ off_raw,    // [T] per-table base offsets (i32 or i64)
    float* __restrict__ out)             // [B*T*128] f32 output (fp16-rounded)
{
    const int r0 = blockIdx.x * ROWS_PER_BLOCK + (threadIdx.x >> 5);  // first row
    const int c  = threadIdx.x & 31;         // float4 chunk within the row (0..31)

    // Sniff index width: int64 entries (<2.6M) have zero high words; an int32
    // buffer's "high words" are real indices uniform in [0,100000) -> all-zero
    // probability ~1e-40. Cached broadcast loads, wave-uniform branch.
    const unsigned int* raw32 = (const unsigned int*)cat_raw;
    bool is64 = true;
    #pragma unroll
    for (int i = 0; i < 8; ++i) is64 = is64 && (raw32[2 * i + 1] == 0u);

    long long row[2];
    #pragma unroll
    for (int k = 0; k < 2; ++k) {
        const int r = r0 + k * 8;            // two rows, 8 apart (same block)
        const int t = r % EMB_TABLES;        // table id (magic-multiply)
        if (is64) {
            row[k] = ((const long long*)cat_raw)[r] + ((const long long*)off_raw)[t];
        } else {
            row[k] = (long long)((const int*)cat_raw)[r]
                   + (long long)((const int*)off_raw)[t];
        }
    }

    // Two independent 16 B gathered loads in flight per thread (MLP=2).
    f32x4 v[2];
    #pragma unroll
    for (int k = 0; k < 2; ++k)
        v[k] = reinterpret_cast<const f32x4*>(
                   weights + (size_t)row[k] * EMB_DIM)[c];

    #pragma unroll
    for (int k = 0; k < 2; ++k) {
        f32x4 w;
        w.x = __half2float(__float2half(v[k].x));
        w.y = __half2float(__float2half(v[k].y));
        w.z = __half2float(__float2half(v[k].z));
        w.w = __half2float(__float2half(v[k].w));
        // Write-once streaming output: nontemporal (nt), bypass L2/L3 so the
        // gather stream keeps the caches. 512 B contiguous per 32-lane group.
        __builtin_nontemporal_store(
            w, reinterpret_cast<f32x4*>(out + (size_t)(r0 + k * 8) * EMB_DIM) + c);
    }
}

extern "C" void kernel_launch(void* const* d_in, const int* in_sizes, int n_in,
                              void* d_out, int out_size, void* d_ws, size_t ws_size,
                              hipStream_t stream) {
    const void* cat = d_in[0];                         // [B*T] integer indices
    const float* weights = (const float*)d_in[1];      // [2.6M*128] fp32
    const void* offsets = d_in[2];                     // [T] integer offsets
    float* out = (float*)d_out;

    const int blocks = EMB_ROWS / ROWS_PER_BLOCK;      // 851,968 / 16 = 53,248 exact
    JointSparseEmbedding_3496103379186_kernel<<<blocks, 256, 0, stream>>>(
        cat, weights, offsets, out);
}